// Round 7
// baseline (324.702 us; speedup 1.0000x reference)
//
#include <hip/hip_runtime.h>

// GraphSAGE 2-layer, N=50000, E=800000, 64 -> 128 -> 64, fp32.
//   h   = relu(mean_agg(x) @ W1_l + b1 + x @ W1_r)
//   out = mean_agg(h) @ W2_l + b2 + h @ W2_r
// R7:
//  - dense1 LDS union (hs overlays ms/xs after sync): 33.3 -> 16.9 KB/block.
//  - gather: unroll x2, dual accumulators -> 8 row-loads in flight/wave.
//  - gather2 fused with final add (out = mean + q + b2) -> k_final gone.
//  - CSR build without prefix scans: rowptr[i] = atomicAdd(total, deg[i])
//    (bucket order is irrelevant); 3 kernels instead of 5.
// Linearity: mean_agg(h)@W2_l = agg(h@W2_l)/cnt -> layer 2 gathers p = h@W2_l.

#define FMA4(acc, f, w0, w1, w2, w3)                          \
  acc.x += f.x * w0.x + f.y * w1.x + f.z * w2.x + f.w * w3.x; \
  acc.y += f.x * w0.y + f.y * w1.y + f.z * w2.y + f.w * w3.y; \
  acc.z += f.x * w0.z + f.y * w1.z + f.z * w2.z + f.w * w3.z; \
  acc.w += f.x * w0.w + f.y * w1.w + f.z * w2.w + f.w * w3.w;

// ---------------- CSR build (scan-free) ----------------
__global__ __launch_bounds__(256) void k_hist(const int* __restrict__ dst,
                                              int* __restrict__ deg, int E) {
  int e = blockIdx.x * blockDim.x + threadIdx.x;
  if (e < E) atomicAdd(&deg[dst[e]], 1);
}

// rowptr[i] = atomicAdd(total, deg[i]); pos[i] = rowptr[i].
__global__ __launch_bounds__(256) void k_assign(const int* __restrict__ deg,
                                                int* __restrict__ rowptr,
                                                int* __restrict__ pos,
                                                int* __restrict__ total,
                                                int N) {
  int i = blockIdx.x * blockDim.x + threadIdx.x;
  if (i >= N) return;
  int r = atomicAdd(total, deg[i]);
  rowptr[i] = r;
  pos[i] = r;
}

__global__ __launch_bounds__(256) void k_fill(const int* __restrict__ src,
                                              const int* __restrict__ dst,
                                              int* __restrict__ pos,
                                              int* __restrict__ colsrc, int E) {
  int e = blockIdx.x * blockDim.x + threadIdx.x;
  if (e >= E) return;
  int slot = atomicAdd(&pos[dst[e]], 1);
  colsrc[slot] = src[e];
}

// ---------------------------------------------------------------------------
// gather: dstbuf[node] = sum_{row} feat[colsrc[e]] / max(deg,1)  (+ addsrc +
// bias when addsrc != nullptr, i.e. the fused layer-2 epilogue).
// 4 waves/block, 1 node/wave, 4 edge-groups x 16 lanes x float4; edge loop
// unrolled x2 with dual accumulators -> 8 independent row loads in flight.
// ---------------------------------------------------------------------------
__global__ __launch_bounds__(256) void k_gather(
    const float* __restrict__ feat, const int* __restrict__ rowptr,
    const int* __restrict__ deg, const int* __restrict__ colsrc,
    const float* __restrict__ addsrc, const float* __restrict__ bias,
    float* __restrict__ dstbuf, int N) {
  int wave = threadIdx.x >> 6;
  int lane = threadIdx.x & 63;
  int node = blockIdx.x * 4 + wave;
  if (node >= N) return;
  int beg = rowptr[node];
  int d = deg[node];
  int end = beg + d;
  int eg = lane >> 4;
  int c4 = (lane & 15) << 2;
  float4 s0 = make_float4(0.f, 0.f, 0.f, 0.f);
  float4 s1 = s0;
  int e = beg + eg;
  for (; e + 4 < end; e += 8) {
    const float4 v0 =
        *reinterpret_cast<const float4*>(feat + (size_t)colsrc[e] * 64 + c4);
    const float4 v1 = *reinterpret_cast<const float4*>(
        feat + (size_t)colsrc[e + 4] * 64 + c4);
    s0.x += v0.x; s0.y += v0.y; s0.z += v0.z; s0.w += v0.w;
    s1.x += v1.x; s1.y += v1.y; s1.z += v1.z; s1.w += v1.w;
  }
  for (; e < end; e += 4) {
    const float4 v =
        *reinterpret_cast<const float4*>(feat + (size_t)colsrc[e] * 64 + c4);
    s0.x += v.x; s0.y += v.y; s0.z += v.z; s0.w += v.w;
  }
  s0.x += s1.x; s0.y += s1.y; s0.z += s1.z; s0.w += s1.w;
#pragma unroll
  for (int m = 16; m <= 32; m <<= 1) {
    s0.x += __shfl_xor(s0.x, m);
    s0.y += __shfl_xor(s0.y, m);
    s0.z += __shfl_xor(s0.z, m);
    s0.w += __shfl_xor(s0.w, m);
  }
  if (eg == 0) {
    float r = 1.f / fmaxf((float)d, 1.f);
    float4 o = make_float4(s0.x * r, s0.y * r, s0.z * r, s0.w * r);
    if (addsrc != nullptr) {
      float4 a = *(const float4*)&addsrc[(size_t)node * 64 + c4];
      float4 b = *(const float4*)&bias[c4];
      o.x += a.x + b.x;
      o.y += a.y + b.y;
      o.z += a.z + b.z;
      o.w += a.w + b.w;
    }
    *reinterpret_cast<float4*>(dstbuf + (size_t)node * 64 + c4) = o;
  }
}

// ---------------------------------------------------------------------------
// dense1: 32 nodes/block, 256 threads. LDS: ms/xs (16KB) unioned with hs
// (16.9KB, pad 132) -> 16.9KB total.
// Phase 1: thread (jt=tid&31, nt=tid>>5) -> 4x4 reg tile of h.
// Phase 2: waves 0-1 -> p = h@W2l, waves 2-3 -> q = h@W2r.
// ---------------------------------------------------------------------------
__global__ __launch_bounds__(256) void k_dense1(
    const float* __restrict__ x, const float* __restrict__ mean1,
    const float* __restrict__ W1l, const float* __restrict__ b1,
    const float* __restrict__ W1r, const float* __restrict__ W2l,
    const float* __restrict__ W2r, float* __restrict__ p,
    float* __restrict__ q, int N) {
  int i0 = blockIdx.x * 32;
  int tid = threadIdx.x;
  __shared__ float smem[32 * 132];                    // 16896 B
  float(*ms)[64] = (float(*)[64])smem;                // [32][64]
  float(*xs)[64] = (float(*)[64])(smem + 32 * 64);    // [32][64]
  float(*hs)[132] = (float(*)[132])smem;              // overlays after sync

  // stage features
  for (int t = tid; t < 512; t += 256) {
    int n = t >> 4;
    int c4 = (t & 15) << 2;
    int node = i0 + n;
    float4 zm, zx;
    if (node < N) {
      zm = *(const float4*)&mean1[(size_t)node * 64 + c4];
      zx = *(const float4*)&x[(size_t)node * 64 + c4];
    } else {
      zm = make_float4(0.f, 0.f, 0.f, 0.f);
      zx = zm;
    }
    *(float4*)&ms[n][c4] = zm;
    *(float4*)&xs[n][c4] = zx;
  }
  __syncthreads();

  // ---- phase 1 ----
  int jt = tid & 31;
  int j0 = jt << 2;
  int nt = tid >> 5;
  int n0 = nt << 2;
  float4 acc[4];
  {
    float4 bj = *(const float4*)&b1[j0];
    acc[0] = bj; acc[1] = bj; acc[2] = bj; acc[3] = bj;
  }
  for (int k0 = 0; k0 < 64; k0 += 4) {
    float4 wl[4], wr[4];
#pragma unroll
    for (int kk = 0; kk < 4; ++kk) {
      wl[kk] = *(const float4*)&W1l[(size_t)(k0 + kk) * 128 + j0];
      wr[kk] = *(const float4*)&W1r[(size_t)(k0 + kk) * 128 + j0];
    }
#pragma unroll
    for (int n = 0; n < 4; ++n) {
      float4 m4 = *(const float4*)&ms[n0 + n][k0];
      float4 x4 = *(const float4*)&xs[n0 + n][k0];
      FMA4(acc[n], m4, wl[0], wl[1], wl[2], wl[3]);
      FMA4(acc[n], x4, wr[0], wr[1], wr[2], wr[3]);
    }
  }
  __syncthreads();  // all reads of ms/xs done before hs overlays them

#pragma unroll
  for (int n = 0; n < 4; ++n) {
    float4 v = acc[n];
    v.x = fmaxf(v.x, 0.f);
    v.y = fmaxf(v.y, 0.f);
    v.z = fmaxf(v.z, 0.f);
    v.w = fmaxf(v.w, 0.f);
    *(float4*)&hs[n0 + n][j0] = v;
  }
  __syncthreads();

  // ---- phase 2 ----
  const float* W = (tid < 128) ? W2l : W2r;
  float* ob = (tid < 128) ? p : q;
  int t2 = tid & 127;
  int jj0 = (t2 & 15) << 2;
  int nn0 = (t2 >> 4) << 2;
  float4 pa[4];
  pa[0] = make_float4(0.f, 0.f, 0.f, 0.f);
  pa[1] = pa[0]; pa[2] = pa[0]; pa[3] = pa[0];
  for (int k0 = 0; k0 < 128; k0 += 4) {
    float4 w[4];
#pragma unroll
    for (int kk = 0; kk < 4; ++kk)
      w[kk] = *(const float4*)&W[(size_t)(k0 + kk) * 64 + jj0];
#pragma unroll
    for (int n = 0; n < 4; ++n) {
      float4 h4 = *(const float4*)&hs[nn0 + n][k0];
      FMA4(pa[n], h4, w[0], w[1], w[2], w[3]);
    }
  }
#pragma unroll
  for (int n = 0; n < 4; ++n) {
    int node = i0 + nn0 + n;
    if (node < N) *(float4*)&ob[(size_t)node * 64 + jj0] = pa[n];
  }
}

extern "C" void kernel_launch(void* const* d_in, const int* in_sizes, int n_in,
                              void* d_out, int out_size, void* d_ws,
                              size_t ws_size, hipStream_t stream) {
  const float* x = (const float*)d_in[0];
  const int* ei = (const int*)d_in[1];
  const float* W1l = (const float*)d_in[2];
  const float* b1 = (const float*)d_in[3];
  const float* W1r = (const float*)d_in[4];
  const float* W2l = (const float*)d_in[5];
  const float* b2 = (const float*)d_in[6];
  const float* W2r = (const float*)d_in[7];
  float* out = (float*)d_out;

  const int N = in_sizes[0] / 64;  // 50000
  const int E = in_sizes[1] / 2;   // 800000
  const int* src = ei;
  const int* dst = ei + E;

  // ws: int deg[N] | int total[1] | rowptr[N] | pos[N] | colsrc[E]
  //   | float mean[N*64] | p[N*64] | q[N*64]
  int* deg = (int*)d_ws;
  int* total = deg + N;
  int* rowptr = total + 1;
  int* pos = rowptr + N;
  int* colsrc = pos + N;
  float* mean = (float*)(colsrc + E);
  float* p = mean + (size_t)N * 64;
  float* q = p + (size_t)N * 64;

  hipMemsetAsync(deg, 0, (size_t)(N + 1) * sizeof(int), stream);
  k_hist<<<(E + 255) / 256, 256, 0, stream>>>(dst, deg, E);
  k_assign<<<(N + 255) / 256, 256, 0, stream>>>(deg, rowptr, pos, total, N);
  k_fill<<<(E + 255) / 256, 256, 0, stream>>>(src, dst, pos, colsrc, E);

  int nblk4 = (N + 3) / 4;     // gather blocks
  int nblk32 = (N + 31) / 32;  // dense blocks
  k_gather<<<nblk4, 256, 0, stream>>>(x, rowptr, deg, colsrc, nullptr, nullptr,
                                      mean, N);
  k_dense1<<<nblk32, 256, 0, stream>>>(x, mean, W1l, b1, W1r, W2l, W2r, p, q,
                                       N);
  k_gather<<<nblk4, 256, 0, stream>>>(p, rowptr, deg, colsrc, q, b2, out, N);
}